// Round 5
// baseline (174.623 us; speedup 1.0000x reference)
//
#include <hip/hip_runtime.h>

// YOLO-style loss, MI355X.
// loss = (2*sum((p_box - t_box)^2) + sum(mask ? CE : 0)) / 512
// channels: box = {0..3, 24..27}; cls = {8..27}; 4..7 entirely unused.
// Per 28-float cell, float4 chunks: c4=0 box, c4=1 UNUSED (skipped), c4=2..6 cls,
// c4=6 doubles as box. Thread-per-cell; the wave's 6 loads/tensor cover a
// contiguous 7 KB span (all bytes consumed via L1), no LDS, no mid-kernel barriers.
//
// *** ROUND-5 TIMING PROBE ***: kernel launched 3x — two dummy passes read cold
// poisoned d_ws (same byte volume, results discarded into a far ws sink), the
// real pass reads the inputs. k_cold = (dur_us - 115.7)/2 separates kernel time
// from the harness's fixed restore/poison floor. Probe removed next round.

#define C_CLS 20
#define D_CH 28
#define BATCH_N 512
#define CELLS (BATCH_N * 28 * 28)     // 401408
#define BLOCK 256
#define NBLOCKS (CELLS / BLOCK)       // 1568, exact
#define REG_FLOATS ((size_t)CELLS * D_CH)   // 11,239,424 floats = 44.96 MB

__global__ __launch_bounds__(BLOCK) void yolo_cell_kernel(
    const float* __restrict__ preds,
    const float* __restrict__ tgts,
    float* __restrict__ sink)
{
    const int tid  = threadIdx.x;
    const int cell = blockIdx.x * BLOCK + tid;
    const size_t b = (size_t)cell * 7;            // float4 index of cell start
    const float4* p4 = reinterpret_cast<const float4*>(preds);
    const float4* t4 = reinterpret_cast<const float4*>(tgts);

    // ---- 12 loads, chunk 1 skipped (channels 4..7 unused) ----
    float4 P0 = p4[b + 0], P2 = p4[b + 2], P3 = p4[b + 3];
    float4 P4 = p4[b + 4], P5 = p4[b + 5], P6 = p4[b + 6];
    float4 T0 = t4[b + 0], T2 = t4[b + 2], T3 = t4[b + 3];
    float4 T4 = t4[b + 4], T5 = t4[b + 5], T6 = t4[b + 6];

    // ---- coord: chunks 0 and 6 ----
    float coord = 0.0f;
    {
        float d;
        d = P0.x - T0.x; coord = fmaf(d, d, coord);
        d = P0.y - T0.y; coord = fmaf(d, d, coord);
        d = P0.z - T0.z; coord = fmaf(d, d, coord);
        d = P0.w - T0.w; coord = fmaf(d, d, coord);
        d = P6.x - T6.x; coord = fmaf(d, d, coord);
        d = P6.y - T6.y; coord = fmaf(d, d, coord);
        d = P6.z - T6.z; coord = fmaf(d, d, coord);
        d = P6.w - T6.w; coord = fmaf(d, d, coord);
    }

    // ---- CE: pred cls chunks 2..6 ----
    float pc[C_CLS];
    pc[0]=P2.x; pc[1]=P2.y; pc[2]=P2.z; pc[3]=P2.w;
    pc[4]=P3.x; pc[5]=P3.y; pc[6]=P3.z; pc[7]=P3.w;
    pc[8]=P4.x; pc[9]=P4.y; pc[10]=P4.z; pc[11]=P4.w;
    pc[12]=P5.x; pc[13]=P5.y; pc[14]=P5.z; pc[15]=P5.w;
    pc[16]=P6.x; pc[17]=P6.y; pc[18]=P6.z; pc[19]=P6.w;

    float m = pc[0];
    #pragma unroll
    for (int j = 1; j < C_CLS; ++j) m = fmaxf(m, pc[j]);
    float se = 0.0f;
    #pragma unroll
    for (int j = 0; j < C_CLS; ++j) se += __expf(pc[j] - m);

    // target cls: mask-sum + first-argmax (ascending order + strict >)
    float tc[C_CLS];
    tc[0]=T2.x; tc[1]=T2.y; tc[2]=T2.z; tc[3]=T2.w;
    tc[4]=T3.x; tc[5]=T3.y; tc[6]=T3.z; tc[7]=T3.w;
    tc[8]=T4.x; tc[9]=T4.y; tc[10]=T4.z; tc[11]=T4.w;
    tc[12]=T5.x; tc[13]=T5.y; tc[14]=T5.z; tc[15]=T5.w;
    tc[16]=T6.x; tc[17]=T6.y; tc[18]=T6.z; tc[19]=T6.w;

    float tsum = 0.0f, tmax = -INFINITY;
    int lab = 0;
    #pragma unroll
    for (int j = 0; j < C_CLS; ++j) {
        tsum += tc[j];
        if (tc[j] > tmax) { tmax = tc[j]; lab = j; }
    }
    float plab = pc[0];
    #pragma unroll
    for (int j = 1; j < C_CLS; ++j) plab = (lab == j) ? pc[j] : plab;
    float ce = -(plab - m - __logf(se));

    float loss = 2.0f * coord + ((tsum > 0.0f) ? ce : 0.0f);

    // ---- wave + block reduce, one atomic per block ----
    #pragma unroll
    for (int off = 32; off > 0; off >>= 1) loss += __shfl_down(loss, off, 64);

    __shared__ float sm[BLOCK / 64];
    const int wid  = tid >> 6;
    const int lane = tid & 63;
    if (lane == 0) sm[wid] = loss;
    __syncthreads();
    if (tid == 0) {
        float s = sm[0] + sm[1] + sm[2] + sm[3];
        atomicAdd(sink, s * (1.0f / (float)BATCH_N));
    }
}

extern "C" void kernel_launch(void* const* d_in, const int* in_sizes, int n_in,
                              void* d_out, int out_size, void* d_ws, size_t ws_size,
                              hipStream_t stream)
{
    const float* preds = (const float*)d_in[0];
    const float* tgts  = (const float*)d_in[1];
    float* out = (float*)d_out;
    float* ws  = (float*)d_ws;

    hipMemsetAsync(out, 0, (size_t)out_size * sizeof(float), stream);

    // --- timing probe: two dummy passes over cold poisoned ws (same byte volume).
    // 0xAAAAAAAA as f32 = -3.03e-13: exp/log paths stay finite; tsum<0 => CE masked.
    const size_t need = 4 * REG_FLOATS + 64;          // two 45MB slabs x2 + sink pad
    if (ws_size >= (need + 64) * sizeof(float)) {
        float* sinkA = ws + 4 * REG_FLOATS;
        float* sinkB = sinkA + 16;
        yolo_cell_kernel<<<NBLOCKS, BLOCK, 0, stream>>>(ws,                 ws + REG_FLOATS,     sinkA);
        yolo_cell_kernel<<<NBLOCKS, BLOCK, 0, stream>>>(ws + 2*REG_FLOATS,  ws + 3*REG_FLOATS,   sinkB);
    }

    // --- real pass ---
    yolo_cell_kernel<<<NBLOCKS, BLOCK, 0, stream>>>(preds, tgts, out);
}

// Round 6
// 172.506 us; speedup vs baseline: 1.0123x; 1.0123x over previous
//
#include <hip/hip_runtime.h>

// YOLO-style loss, MI355X.
// loss = (2*sum((p_box - t_box)^2) + sum(mask ? CE : 0)) / 512
// channels: box = {0..3, 24..27}; cls = {8..27}; 4..7 unused.
// float4 chunks per 28-float cell: c4=0 box, c4=1 unused, c4=2..6 cls (20 floats),
// c4=6 doubles as box (24..27).
//
// Structure: fully-coalesced global loads (lane stride 16 B — one wave instruction
// covers a contiguous 4 KB span, no transaction amplification); coord computed
// inline from registers (element-separable); cls chunks redistributed cell-major
// through two 20 KB LDS buffers with a SINGLE barrier. Packed 80 B rows: read
// banks (20*cell + 4*s) mod 32 hit all 32 banks uniformly 8x per b128 wave read
// = conflict-free optimum.
//
// *** ROUND-6 PROBE (kept from round 5) ***: two dummy passes over cold poisoned
// d_ws isolate the kernel's cold-HBM time from the ~86 us harness floor:
//   k_cold = (dur_us - floor) / 3,  floor ~= 86 us (round-4/5 consistent).

#define C_CLS 20
#define D_CH 28
#define BATCH_N 512
#define CELLS (BATCH_N * 28 * 28)     // 401408
#define BLOCK 256
#define CPB 256                       // cells per block
#define NBLOCKS (CELLS / CPB)         // 1568, exact
#define REG_FLOATS ((size_t)CELLS * D_CH)   // 11,239,424 floats = 44.96 MB

__global__ __launch_bounds__(BLOCK) void yolo_staged_kernel(
    const float* __restrict__ preds,
    const float* __restrict__ tgts,
    float* __restrict__ out)
{
    __shared__ float ldsP[CPB * C_CLS];   // 20 KB
    __shared__ float ldsT[CPB * C_CLS];   // 20 KB
    __shared__ float sm[BLOCK / 64];

    const int tid = threadIdx.x;
    const float* pBase = preds + (size_t)blockIdx.x * (CPB * D_CH);
    const float* tBase = tgts  + (size_t)blockIdx.x * (CPB * D_CH);
    const float4* gp = reinterpret_cast<const float4*>(pBase);
    const float4* gt = reinterpret_cast<const float4*>(tBase);

    // ---- coalesced loads: 7 float4 per tensor per thread, lane stride 16 B ----
    float4 vp[7], vt[7];
    #pragma unroll
    for (int k = 0; k < 7; ++k) vp[k] = gp[tid + BLOCK * k];
    #pragma unroll
    for (int k = 0; k < 7; ++k) vt[k] = gt[tid + BLOCK * k];

    // ---- coord inline: each thread owns exactly one c4==0 and one c4==6 chunk
    //      (tid+256k mod 7 = tid+4k mod 7 walks all residues, gcd(4,7)=1) ----
    float coord = 0.0f;
    #pragma unroll
    for (int k = 0; k < 7; ++k) {
        const int c4 = (tid + BLOCK * k) % 7;
        if (c4 == 0 || c4 == 6) {
            float dx = vp[k].x - vt[k].x; coord = fmaf(dx, dx, coord);
            float dy = vp[k].y - vt[k].y; coord = fmaf(dy, dy, coord);
            float dz = vp[k].z - vt[k].z; coord = fmaf(dz, dz, coord);
            float dw = vp[k].w - vt[k].w; coord = fmaf(dw, dw, coord);
        }
    }

    // ---- stage both cls streams (c4 in 2..6), packed 80 B rows, ONE barrier ----
    #pragma unroll
    for (int k = 0; k < 7; ++k) {
        const int idx  = tid + BLOCK * k;
        const int cell = idx / 7;
        const int c4   = idx - cell * 7;
        if (c4 >= 2) {
            *reinterpret_cast<float4*>(&ldsP[cell * C_CLS + (c4 - 2) * 4]) = vp[k];
            *reinterpret_cast<float4*>(&ldsT[cell * C_CLS + (c4 - 2) * 4]) = vt[k];
        }
    }
    __syncthreads();

    // ---- per-cell CE from LDS (thread tid <-> cell tid) ----
    float pc[C_CLS];
    #pragma unroll
    for (int s = 0; s < 5; ++s) {
        float4 a = *reinterpret_cast<const float4*>(&ldsP[tid * C_CLS + s * 4]);
        pc[4*s+0] = a.x; pc[4*s+1] = a.y; pc[4*s+2] = a.z; pc[4*s+3] = a.w;
    }
    float m = pc[0];
    #pragma unroll
    for (int j = 1; j < C_CLS; ++j) m = fmaxf(m, pc[j]);
    float se = 0.0f;
    #pragma unroll
    for (int j = 0; j < C_CLS; ++j) se += __expf(pc[j] - m);

    float tsum = 0.0f, tmax = -INFINITY;
    int lab = 0;
    #pragma unroll
    for (int s = 0; s < 5; ++s) {
        float4 a = *reinterpret_cast<const float4*>(&ldsT[tid * C_CLS + s * 4]);
        tsum += a.x + a.y + a.z + a.w;
        if (a.x > tmax) { tmax = a.x; lab = 4*s+0; }   // ascending + strict > = first-max
        if (a.y > tmax) { tmax = a.y; lab = 4*s+1; }
        if (a.z > tmax) { tmax = a.z; lab = 4*s+2; }
        if (a.w > tmax) { tmax = a.w; lab = 4*s+3; }
    }
    float plab = pc[0];
    #pragma unroll
    for (int j = 1; j < C_CLS; ++j) plab = (lab == j) ? pc[j] : plab;
    float ce = -(plab - m - __logf(se));

    float loss = 2.0f * coord + ((tsum > 0.0f) ? ce : 0.0f);

    // ---- wave + block reduce, one atomic per block ----
    #pragma unroll
    for (int off = 32; off > 0; off >>= 1) loss += __shfl_down(loss, off, 64);

    const int wid  = tid >> 6;
    const int lane = tid & 63;
    if (lane == 0) sm[wid] = loss;
    __syncthreads();
    if (tid == 0) {
        float s = sm[0] + sm[1] + sm[2] + sm[3];
        atomicAdd(out, s * (1.0f / (float)BATCH_N));
    }
}

extern "C" void kernel_launch(void* const* d_in, const int* in_sizes, int n_in,
                              void* d_out, int out_size, void* d_ws, size_t ws_size,
                              hipStream_t stream)
{
    const float* preds = (const float*)d_in[0];
    const float* tgts  = (const float*)d_in[1];
    float* out = (float*)d_out;
    float* ws  = (float*)d_ws;

    hipMemsetAsync(out, 0, (size_t)out_size * sizeof(float), stream);

    // --- timing probe: two dummy passes over cold poisoned ws (same byte volume).
    // 0xAAAAAAAA as f32 = -3.03e-13: finite everywhere; tsum<0 => CE masked.
    const size_t need = 4 * REG_FLOATS + 64;
    if (ws_size >= (need + 64) * sizeof(float)) {
        float* sinkA = ws + 4 * REG_FLOATS;
        float* sinkB = sinkA + 16;
        yolo_staged_kernel<<<NBLOCKS, BLOCK, 0, stream>>>(ws,                ws + REG_FLOATS,   sinkA);
        yolo_staged_kernel<<<NBLOCKS, BLOCK, 0, stream>>>(ws + 2*REG_FLOATS, ws + 3*REG_FLOATS, sinkB);
    }

    // --- real pass ---
    yolo_staged_kernel<<<NBLOCKS, BLOCK, 0, stream>>>(preds, tgts, out);
}